// Round 8
// baseline (222.487 us; speedup 1.0000x reference)
//
#include <hip/hip_runtime.h>

#define D_MODEL 1024
#define NHEADS  16
#define HDIM    64
#define BATCH   2
#define SEQ     2048
#define ROWS    (BATCH*SEQ)      // 4096
#define CHUNK   128
#define NCHUNK  (SEQ/CHUNK)      // 16
#define LN_EPS  1e-3f

typedef unsigned short ushort_t;
typedef __attribute__((ext_vector_type(4))) float          f32x4;
typedef __attribute__((ext_vector_type(8))) short          s16x8;
typedef __attribute__((ext_vector_type(4))) unsigned short u16x4;
typedef __attribute__((ext_vector_type(8))) unsigned short u16x8;

__device__ __forceinline__ ushort_t f2b(float f) {
    union { float f; unsigned int u; } v; v.f = f;
    unsigned int r = v.u + 0x7fffu + ((v.u >> 16) & 1u);
    return (ushort_t)(r >> 16);
}
__device__ __forceinline__ float b2f(ushort_t b) {
    union { unsigned int u; float f; } v; v.u = ((unsigned int)b) << 16;
    return v.f;
}

// async 16B global -> LDS (wave-uniform base + lane*16; m97 pattern)
__device__ __forceinline__ void async_load16(const ushort_t* g, ushort_t* l) {
    __builtin_amdgcn_global_load_lds(
        (const __attribute__((address_space(1))) unsigned int*)(g),
        (__attribute__((address_space(3))) unsigned int*)(l),
        16, 0, 0);
}

// ---------------------------------------------- prep: cast x + W transposes + zero rowstats
__global__ __launch_bounds__(256) void prep_kernel(
        const float* __restrict__ x,
        const float* __restrict__ Wq, const float* __restrict__ Wk,
        const float* __restrict__ Wv, const float* __restrict__ Wg,
        const float* __restrict__ Wo,
        ushort_t* __restrict__ xb, ushort_t* __restrict__ WcatT,
        ushort_t* __restrict__ WoT, float* __restrict__ rowstats) {
    __shared__ float tile[32][33];
    int bid = blockIdx.x, t = threadIdx.x;
    if (bid < 4096) {                       // cast x (+ zero rowstats in first 8 blocks)
        if (bid < 8)
            *(f32x4*)(rowstats + (bid * 256 + t) * 4) = (f32x4)0.0f;  // 8192 floats
        int idx = (bid * 256 + t) * 4;
        f32x4 v = *(const f32x4*)(x + idx);
        u16x4 o;
        o.x = f2b(v.x); o.y = f2b(v.y); o.z = f2b(v.z); o.w = f2b(v.w);
        *(u16x4*)(xb + idx) = o;
        return;
    }
    int zb = bid - 4096;
    int z = zb >> 10;
    int rem = zb & 1023;
    int bx = rem & 31, by = rem >> 5;
    const float* W = (z == 0) ? Wq : (z == 1) ? Wk : (z == 2) ? Wv : (z == 3) ? Wg : Wo;
    ushort_t* dst = (z < 4) ? (WcatT + (size_t)z * 1024 * 1024) : WoT;
    int n0 = bx * 32, k0 = by * 32;
    int tx = t & 31, ty = t >> 5;
#pragma unroll
    for (int i = 0; i < 4; i++) {
        int k = k0 + ty + i * 8;
        tile[ty + i * 8][tx] = W[(size_t)k * 1024 + n0 + tx];
    }
    __syncthreads();
#pragma unroll
    for (int i = 0; i < 4; i++) {
        int n = n0 + ty + i * 8;
        dst[(size_t)n * 1024 + k0 + tx] = f2b(tile[tx][ty + i * 8]);
    }
}

// ---------------------------------------------------------------- bf16 MFMA GEMM
// C = A @ B, BT[n][k]. async width=16 staging, BK=128 (64 KB LDS), XOR-swizzled
// 16B blocks (key r&15; fragment un-swizzle ((kk>>3)+qd)^ln).
// mode 0: N=4096 QKVG epilogue -> Y bf16 (Q*1/8, G = swish(.+bias))
// mode 1: N=1024 -> Fout fp32 = C + bias
__global__ __launch_bounds__(256, 2) void gemm_kernel(
        const ushort_t* __restrict__ A, const ushort_t* __restrict__ BT,
        int K, int N, int mode, const float* __restrict__ bias,
        ushort_t* __restrict__ Yout, float* __restrict__ Fout) {
    extern __shared__ char smem[];
    ushort_t* As = (ushort_t*)smem;          // [128][128] swizzled
    ushort_t* Bs = As + 128 * 128;
    int t = threadIdx.x;
    int row0 = blockIdx.y * 128, col0 = blockIdx.x * 128;
    int w = t >> 6, lane = t & 63;
    int wr = (w >> 1) * 64, wc = (w & 1) * 64;
    int qd = lane >> 4, ln = lane & 15;

    f32x4 acc[4][4];
#pragma unroll
    for (int i = 0; i < 4; i++)
#pragma unroll
        for (int j = 0; j < 4; j++) acc[i][j] = (f32x4)0.0f;

    for (int k0 = 0; k0 < K; k0 += 128) {
#pragma unroll
        for (int p = 0; p < 8; p++) {
            int g = p * 256 + t;
            int r = g >> 4;                  // tile row 0..127
            int kb = g & 15;                 // 16B block slot
            int kbs = kb ^ (r & 15);         // swizzled global source block
            async_load16(A + (size_t)(row0 + r) * K + k0 + kbs * 8, As + g * 8);
            async_load16(BT + (size_t)(col0 + r) * K + k0 + kbs * 8, Bs + g * 8);
        }
        __syncthreads();
#pragma unroll
        for (int kk = 0; kk < 128; kk += 32) {
            s16x8 af[4], bf[4];
            int kxa = ((kk >> 3) + qd) ^ ln;
#pragma unroll
            for (int i = 0; i < 4; i++)
                af[i] = *(const s16x8*)(As + (wr + i * 16 + ln) * 128 + kxa * 8);
#pragma unroll
            for (int j = 0; j < 4; j++)
                bf[j] = *(const s16x8*)(Bs + (wc + j * 16 + ln) * 128 + kxa * 8);
#pragma unroll
            for (int i = 0; i < 4; i++)
#pragma unroll
                for (int j = 0; j < 4; j++)
                    acc[i][j] = __builtin_amdgcn_mfma_f32_16x16x32_bf16(
                        af[i], bf[j], acc[i][j], 0, 0, 0);
        }
        __syncthreads();
    }

#pragma unroll
    for (int i = 0; i < 4; i++)
#pragma unroll
        for (int j = 0; j < 4; j++) {
            int n = col0 + wc + j * 16 + ln;
            int region = n >> 10;
#pragma unroll
            for (int r = 0; r < 4; r++) {
                int m = row0 + wr + i * 16 + qd * 4 + r;
                float v = acc[i][j][r];
                if (mode == 0) {
                    if (region == 0) v *= 0.125f;
                    else if (region == 3) {
                        v += bias[n & 1023];
                        v = v / (1.0f + __expf(-v));
                    }
                    Yout[(size_t)m * N + n] = f2b(v);
                } else {
                    Fout[(size_t)m * N + n] = v + bias[n];
                }
            }
        }
}

// ------------------------------------- per-chunk decayed KV state (MFMA), once per chunk
// AstT[d][e] = sum_j V[j][d] * K[j][e] * g^(127-j);  M=64(d), N=64(e), K=128(j)
#define SJ 136
__global__ __launch_bounds__(256) void chunk_states_kernel(const ushort_t* __restrict__ Y,
                                                           float* __restrict__ Astate) {
    __shared__ ushort_t Ktd[64 * SJ];   // [e][j]  decayed K^T
    __shared__ ushort_t Vtd[64 * SJ];   // [d][j]  V^T
    int c = blockIdx.x, h = blockIdx.y, b = blockIdx.z;
    int t = threadIdx.x;
    float gamma = 1.0f - exp2f(-5.0f - (float)h);
    float l2g = log2f(gamma);
    int row0 = b * SEQ + c * CHUNK;
    int colK = D_MODEL + h * HDIM;

    {
        int dgi = t & 7, jg = t >> 3;
        u16x8 k8[4], v8[4];
        float dec[4];
#pragma unroll
        for (int r = 0; r < 4; r++) {
            int j = jg * 4 + r;
            size_t src = (size_t)(row0 + j) * 4096 + colK + dgi * 8;
            k8[r] = *(const u16x8*)(Y + src);
            v8[r] = *(const u16x8*)(Y + src + D_MODEL);
            dec[r] = exp2f((float)(127 - j) * l2g);
        }
#pragma unroll
        for (int q = 0; q < 8; q++) {
            int qq = q ^ dgi;                   // bank-decorrelating permutation
            u16x4 pk, pv;
#pragma unroll
            for (int r = 0; r < 4; r++) {
                pk[r] = f2b(b2f(k8[r][qq]) * dec[r]);
                pv[r] = v8[r][qq];
            }
            *(u16x4*)(Ktd + (dgi * 8 + qq) * SJ + jg * 4) = pk;
            *(u16x4*)(Vtd + (dgi * 8 + qq) * SJ + jg * 4) = pv;
        }
    }
    __syncthreads();

    int w = t >> 6, lane = t & 63;
    int wr = w * 16;                 // this wave's 16 d-rows
    int qd = lane >> 4, ln = lane & 15;

    s16x8 af[4];
#pragma unroll
    for (int ks = 0; ks < 4; ks++)
        af[ks] = *(const s16x8*)(Vtd + (wr + ln) * SJ + ks * 32 + qd * 8);

    f32x4 acc[4];
#pragma unroll
    for (int nt = 0; nt < 4; nt++) {
        acc[nt] = (f32x4)0.0f;
#pragma unroll
        for (int ks = 0; ks < 4; ks++) {
            s16x8 bf = *(const s16x8*)(Ktd + (nt * 16 + ln) * SJ + ks * 32 + qd * 8);
            acc[nt] = __builtin_amdgcn_mfma_f32_16x16x32_bf16(af[ks], bf, acc[nt], 0, 0, 0);
        }
    }

    size_t base = ((size_t)((b * NHEADS + h) * NCHUNK + c)) * 4096;
#pragma unroll
    for (int nt = 0; nt < 4; nt++)
#pragma unroll
        for (int r = 0; r < 4; r++)
            Astate[base + (size_t)(wr + qd * 4 + r) * 64 + nt * 16 + ln] = acc[nt][r];
}

// --------------------------------------------- retention output (prefix-combine + MFMA)
// S_prev = sum_{cp<c} gC^(c-1-cp) A_cp  (elementwise, registers, prefetched)
// out[i][d] = g^(i+1)*(Q_i.S[:,d]) + sum_{j<=i} g^(i-j)(Q_i.K_j)V_j[d]
// ret written bf16; per-row (sum,sumsq) of rounded values atomically -> rowstats.
#define LDW 72
#define VT_LDW 136
#define CO_ELEMS (128*LDW*2 + 64*LDW*2 + 64*VT_LDW)   // 36352 elems = 72704 B
__global__ __launch_bounds__(256, 2) void retention_kernel(const ushort_t* __restrict__ Y,
                                                           const float* __restrict__ Astate,
                                                           ushort_t* __restrict__ ret,
                                                           float* __restrict__ rowstats) {
    extern __shared__ char smem[];
    ushort_t* Qs   = (ushort_t*)smem;            // [128][72]
    ushort_t* Kc   = Qs + 128 * LDW;             // [128][72]
    ushort_t* Sphi = Kc + 128 * LDW;             // [64][72]   S^T hi [d][e]
    ushort_t* Splo = Sphi + 64 * LDW;            // [64][72]   S^T lo
    ushort_t* Vt   = Splo + 64 * LDW;            // [64][136]  V^T[d][j] (chunk c)
    ushort_t* Pl   = Qs;                         // [128][136] phase-3 overlay

    int bx = blockIdx.x, h = blockIdx.y, b = blockIdx.z;
    // pair-balance: consecutive bx pairs sum to NCHUNK-1 so co-resident blocks
    // average 7.5 prefix stages instead of 0..15 skew
    int c = (bx & 1) ? (NCHUNK - 1 - (bx >> 1)) : (bx >> 1);
    int t = threadIdx.x;
    float gamma = 1.0f - exp2f(-5.0f - (float)h);
    float l2g = log2f(gamma);
    float gC = exp2f(128.0f * l2g);
    int row0 = b * SEQ + c * CHUNK;

    int w = t >> 6, lane = t & 63;
    int qd = lane >> 4, ln = lane & 15;
    int dgi = t & 7, jg = t >> 3;

    // ---- stage V_c transposed into Vt
    {
        u16x8 v8[4];
#pragma unroll
        for (int r = 0; r < 4; r++)
            v8[r] = *(const u16x8*)(Y + (size_t)(row0 + jg * 4 + r) * 4096
                                      + 2 * D_MODEL + h * HDIM + dgi * 8);
#pragma unroll
        for (int q = 0; q < 8; q++) {
            int qq = q ^ dgi;
            u16x4 pv;
#pragma unroll
            for (int r = 0; r < 4; r++) pv[r] = v8[r][qq];
            *(u16x4*)(Vt + (dgi * 8 + qq) * VT_LDW + jg * 4) = pv;
        }
    }

    // ---- stage Q,K (row-major)
    for (int g = t; g < 1024; g += 256) {
        int i = g >> 3, dg = (g & 7) * 8;
        size_t src = (size_t)(row0 + i) * 4096 + h * HDIM + dg;
        *(u16x8*)(Qs + i * LDW + dg) = *(const u16x8*)(Y + src);
        *(u16x8*)(Kc + i * LDW + dg) = *(const u16x8*)(Y + src + D_MODEL);
    }

    // ---- prefix combine: S = S*gC + A_cp (register double-buffered prefetch)
    {
        f32x4 acc4[4];
#pragma unroll
        for (int k4 = 0; k4 < 4; k4++) acc4[k4] = (f32x4)0.0f;
        size_t abase = ((size_t)((b * NHEADS + h) * NCHUNK)) * 4096 + t * 16;
        f32x4 a_cur[4];
        if (c > 0) {
#pragma unroll
            for (int k4 = 0; k4 < 4; k4++)
                a_cur[k4] = *(const f32x4*)(Astate + abase + k4 * 4);
        }
        for (int cp = 0; cp < c; cp++) {
            f32x4 a_nxt[4];
            if (cp + 1 < c) {
#pragma unroll
                for (int k4 = 0; k4 < 4; k4++)
                    a_nxt[k4] = *(const f32x4*)(Astate + abase + (size_t)(cp + 1) * 4096 + k4 * 4);
            }
#pragma unroll
            for (int k4 = 0; k4 < 4; k4++)
                acc4[k4] = acc4[k4] * gC + a_cur[k4];
#pragma unroll
            for (int k4 = 0; k4 < 4; k4++) a_cur[k4] = a_nxt[k4];
        }
        int d = t >> 2, e0 = (t & 3) * 16;
#pragma unroll
        for (int k4 = 0; k4 < 4; k4++) {
            u16x4 hi4, lo4;
#pragma unroll
            for (int k2 = 0; k2 < 4; k2++) {
                float s = acc4[k4][k2];
                ushort_t hb = f2b(s);
                hi4[k2] = hb;
                lo4[k2] = f2b(s - b2f(hb));
            }
            *(u16x4*)(Sphi + d * LDW + e0 + k4 * 4) = hi4;
            *(u16x4*)(Splo + d * LDW + e0 + k4 * 4) = lo4;
        }
    }
    __syncthreads();

    int wr2 = w * 32;    // wave's 32 output rows

    s16x8 aq[2][2];
#pragma unroll
    for (int mt = 0; mt < 2; mt++)
#pragma unroll
        for (int ks = 0; ks < 2; ks++)
            aq[mt][ks] = *(const s16x8*)(Qs + (wr2 + mt * 16 + ln) * LDW + ks * 32 + qd * 8);

    float prow[2][4], pcolm[8];
#pragma unroll
    for (int mt = 0; mt < 2; mt++)
#pragma unroll
        for (int r = 0; r < 4; r++)
            prow[mt][r] = exp2f((float)(wr2 + mt * 16 + qd * 4 + r + 1) * l2g);
#pragma unroll
    for (int nt = 0; nt < 8; nt++)
        pcolm[nt] = exp2f(-(float)(nt * 16 + ln + 1) * l2g);

    // phase 1: out = Q @ S (hi+lo), scaled g^(i+1)
    f32x4 out[2][4];
#pragma unroll
    for (int mt = 0; mt < 2; mt++)
#pragma unroll
        for (int dt = 0; dt < 4; dt++) out[mt][dt] = (f32x4)0.0f;
#pragma unroll
    for (int dt = 0; dt < 4; dt++)
#pragma unroll
        for (int ks = 0; ks < 2; ks++) {
            s16x8 bh_ = *(const s16x8*)(Sphi + (dt * 16 + ln) * LDW + ks * 32 + qd * 8);
            s16x8 bl_ = *(const s16x8*)(Splo + (dt * 16 + ln) * LDW + ks * 32 + qd * 8);
#pragma unroll
            for (int mt = 0; mt < 2; mt++) {
                out[mt][dt] = __builtin_amdgcn_mfma_f32_16x16x32_bf16(
                    aq[mt][ks], bh_, out[mt][dt], 0, 0, 0);
                out[mt][dt] = __builtin_amdgcn_mfma_f32_16x16x32_bf16(
                    aq[mt][ks], bl_, out[mt][dt], 0, 0, 0);
            }
        }
#pragma unroll
    for (int mt = 0; mt < 2; mt++)
#pragma unroll
        for (int dt = 0; dt < 4; dt++)
#pragma unroll
            for (int r = 0; r < 4; r++) out[mt][dt][r] *= prow[mt][r];

    // phase 2: scores = Q @ K^T
    f32x4 sc[2][8];
#pragma unroll
    for (int mt = 0; mt < 2; mt++)
#pragma unroll
        for (int nt = 0; nt < 8; nt++) sc[mt][nt] = (f32x4)0.0f;
#pragma unroll
    for (int nt = 0; nt < 8; nt++)
#pragma unroll
        for (int ks = 0; ks < 2; ks++) {
            s16x8 bk = *(const s16x8*)(Kc + (nt * 16 + ln) * LDW + ks * 32 + qd * 8);
#pragma unroll
            for (int mt = 0; mt < 2; mt++)
                sc[mt][nt] = __builtin_amdgcn_mfma_f32_16x16x32_bf16(
                    aq[mt][ks], bk, sc[mt][nt], 0, 0, 0);
        }
    __syncthreads();

    // decay-mask, P bf16 -> LDS (A-operand layout)
#pragma unroll
    for (int mt = 0; mt < 2; mt++)
#pragma unroll
        for (int nt = 0; nt < 8; nt++) {
            int j = nt * 16 + ln;
#pragma unroll
            for (int r = 0; r < 4; r++) {
                int i = wr2 + mt * 16 + qd * 4 + r;
                float v = (j <= i) ? sc[mt][nt][r] * (prow[mt][r] * pcolm[nt]) : 0.0f;
                Pl[i * VT_LDW + j] = f2b(v);
            }
        }
    __syncthreads();

    // phase 3: out += P @ V
#pragma unroll
    for (int ks = 0; ks < 4; ks++) {
        s16x8 ap[2];
#pragma unroll
        for (int mt = 0; mt < 2; mt++)
            ap[mt] = *(const s16x8*)(Pl + (wr2 + mt * 16 + ln) * VT_LDW + ks * 32 + qd * 8);
#pragma unroll
        for (int dt = 0; dt < 4; dt++) {
            s16x8 bv = *(const s16x8*)(Vt + (dt * 16 + ln) * VT_LDW + ks * 32 + qd * 8);
#pragma unroll
            for (int mt = 0; mt < 2; mt++)
                out[mt][dt] = __builtin_amdgcn_mfma_f32_16x16x32_bf16(
                    ap[mt], bv, out[mt][dt], 0, 0, 0);
        }
    }

    // ---- store bf16 + per-row LN stats of the ROUNDED values
    float psum[2][4], psq[2][4];
#pragma unroll
    for (int mt = 0; mt < 2; mt++)
#pragma unroll
        for (int r = 0; r < 4; r++) { psum[mt][r] = 0.0f; psq[mt][r] = 0.0f; }
#pragma unroll
    for (int mt = 0; mt < 2; mt++)
#pragma unroll
        for (int dt = 0; dt < 4; dt++)
#pragma unroll
            for (int r = 0; r < 4; r++) {
                int i = wr2 + mt * 16 + qd * 4 + r;
                ushort_t hb = f2b(out[mt][dt][r]);
                ret[(size_t)(row0 + i) * D_MODEL + h * HDIM + dt * 16 + ln] = hb;
                float vr = b2f(hb);
                psum[mt][r] += vr;
                psq[mt][r]  += vr * vr;
            }
#pragma unroll
    for (int m = 1; m < 16; m <<= 1)
#pragma unroll
        for (int mt = 0; mt < 2; mt++)
#pragma unroll
            for (int r = 0; r < 4; r++) {
                psum[mt][r] += __shfl_xor(psum[mt][r], m);
                psq[mt][r]  += __shfl_xor(psq[mt][r], m);
            }
    if (ln == 0) {
#pragma unroll
        for (int mt = 0; mt < 2; mt++)
#pragma unroll
            for (int r = 0; r < 4; r++) {
                int i = row0 + wr2 + mt * 16 + qd * 4 + r;
                atomicAdd(rowstats + 2 * i,     psum[mt][r]);
                atomicAdd(rowstats + 2 * i + 1, psq[mt][r]);
            }
    }
}

// ----------------------------------- LayerNorm * gate (elementwise, stats precomputed)
__global__ __launch_bounds__(256) void ln_gate_kernel(const ushort_t* __restrict__ ret,
                                                      const ushort_t* __restrict__ Y,
                                                      const float* __restrict__ rowstats,
                                                      const float* __restrict__ lgam,
                                                      const float* __restrict__ lbet,
                                                      ushort_t* __restrict__ LNG) {
    int row = blockIdx.x, t = threadIdx.x;
    float s  = rowstats[2 * row];
    float sq = rowstats[2 * row + 1];
    float mu  = s * (1.0f / 1024.0f);
    float var = sq * (1.0f / 1024.0f) - mu * mu;
    float inv = rsqrtf(var + LN_EPS);
    int col = t * 4;
    u16x4 rv = *(const u16x4*)(ret + (size_t)row * D_MODEL + col);
    u16x4 ug = *(const u16x4*)(Y + (size_t)row * 4096 + 3 * D_MODEL + col);
    f32x4 ga = *(const f32x4*)(lgam + col);
    f32x4 gb = *(const f32x4*)(lbet + col);
    u16x4 o;
#pragma unroll
    for (int k = 0; k < 4; k++)
        o[k] = f2b(((b2f(rv[k]) - mu) * inv * ga[k] + gb[k]) * b2f(ug[k]));
    *(u16x4*)(LNG + (size_t)row * D_MODEL + col) = o;
}

// ----------------------------------------------------------------------------
extern "C" void kernel_launch(void* const* d_in, const int* in_sizes, int n_in,
                              void* d_out, int out_size, void* d_ws, size_t ws_size,
                              hipStream_t stream) {
    const float* x   = (const float*)d_in[0];
    const float* Wq  = (const float*)d_in[1];
    const float* Wk  = (const float*)d_in[2];
    const float* Wv  = (const float*)d_in[3];
    const float* Wg  = (const float*)d_in[4];
    const float* bg  = (const float*)d_in[5];
    const float* Wo  = (const float*)d_in[6];
    const float* bo  = (const float*)d_in[7];
    const float* lng = (const float*)d_in[8];
    const float* lnb = (const float*)d_in[9];
    float* out = (float*)d_out;

    char* ws = (char*)d_ws;
    ushort_t* xb    = (ushort_t*)(ws);                       //  8 MB  x bf16
    ushort_t* WcatT = (ushort_t*)(ws + (8ull  << 20));       //  8 MB  [Wq|Wk|Wv|Wg]^T bf16
    ushort_t* WoT   = (ushort_t*)(ws + (16ull << 20));       //  2 MB  Wo^T bf16
    ushort_t* Yb    = (ushort_t*)(ws + (18ull << 20));       // 32 MB  [Q/8|K|V|G] bf16
    float*    rstat = (float*)   (ws + (50ull << 20));       // 32 KB  per-row (sum, sumsq)
    ushort_t* retb  = (ushort_t*)(ws + (51ull << 20));       //  8 MB  retention out bf16
    ushort_t* LNGb  = (ushort_t*)(ws + (60ull << 20));       //  8 MB  (ln*G) bf16
    float*    Ast   = (float*)   (ws + (69ull << 20));       //  8 MB  chunk states [d][e] fp32

    const int GEMM_LDS = 2 * 128 * 128 * 2;                  // 65536 B (BK=128)
    const int CO_BYTES = CO_ELEMS * 2;                       // 72704 B

    hipFuncSetAttribute(reinterpret_cast<const void*>(gemm_kernel),
                        hipFuncAttributeMaxDynamicSharedMemorySize, GEMM_LDS);
    hipFuncSetAttribute(reinterpret_cast<const void*>(retention_kernel),
                        hipFuncAttributeMaxDynamicSharedMemorySize, CO_BYTES);

    prep_kernel<<<4096 + 5120, 256, 0, stream>>>(x, Wq, Wk, Wv, Wg, Wo,
                                                 xb, WcatT, WoT, rstat);

    gemm_kernel<<<dim3(32, 32), 256, GEMM_LDS, stream>>>(
        xb, WcatT, 1024, 4096, 0, bg, Yb, (float*)nullptr);

    chunk_states_kernel<<<dim3(NCHUNK, NHEADS, BATCH), 256, 0, stream>>>(Yb, Ast);

    retention_kernel<<<dim3(NCHUNK, NHEADS, BATCH), 256, CO_BYTES, stream>>>(
        Yb, Ast, retb, rstat);

    ln_gate_kernel<<<ROWS, 256, 0, stream>>>(retb, Yb, rstat, lng, lnb, LNGb);

    gemm_kernel<<<dim3(8, 32), 256, GEMM_LDS, stream>>>(
        LNGb, WoT, 1024, 1024, 1, bo, (ushort_t*)nullptr, out);
}

// Round 9
// 207.338 us; speedup vs baseline: 1.0731x; 1.0731x over previous
//
#include <hip/hip_runtime.h>

#define D_MODEL 1024
#define NHEADS  16
#define HDIM    64
#define BATCH   2
#define SEQ     2048
#define ROWS    (BATCH*SEQ)      // 4096
#define CHUNK   128
#define NCHUNK  (SEQ/CHUNK)      // 16
#define LN_EPS  1e-3f

typedef unsigned short ushort_t;
typedef __attribute__((ext_vector_type(4))) float          f32x4;
typedef __attribute__((ext_vector_type(8))) short          s16x8;
typedef __attribute__((ext_vector_type(4))) unsigned short u16x4;
typedef __attribute__((ext_vector_type(8))) unsigned short u16x8;

__device__ __forceinline__ ushort_t f2b(float f) {
    union { float f; unsigned int u; } v; v.f = f;
    unsigned int r = v.u + 0x7fffu + ((v.u >> 16) & 1u);
    return (ushort_t)(r >> 16);
}
__device__ __forceinline__ float b2f(ushort_t b) {
    union { unsigned int u; float f; } v; v.u = ((unsigned int)b) << 16;
    return v.f;
}

// async 16B global -> LDS (wave-uniform base + lane*16; m97 pattern)
__device__ __forceinline__ void async_load16(const ushort_t* g, ushort_t* l) {
    __builtin_amdgcn_global_load_lds(
        (const __attribute__((address_space(1))) unsigned int*)(g),
        (__attribute__((address_space(3))) unsigned int*)(l),
        16, 0, 0);
}

// ---------------------------------------------- prep: cast x + W transposes + zero rowstats
__global__ __launch_bounds__(256) void prep_kernel(
        const float* __restrict__ x,
        const float* __restrict__ Wq, const float* __restrict__ Wk,
        const float* __restrict__ Wv, const float* __restrict__ Wg,
        const float* __restrict__ Wo,
        ushort_t* __restrict__ xb, ushort_t* __restrict__ WcatT,
        ushort_t* __restrict__ WoT, float* __restrict__ rowstats) {
    __shared__ float tile[32][33];
    int bid = blockIdx.x, t = threadIdx.x;
    if (bid < 4096) {                       // cast x (+ zero rowstats in first 8 blocks)
        if (bid < 8)
            *(f32x4*)(rowstats + (bid * 256 + t) * 4) = (f32x4)0.0f;  // 8192 floats
        int idx = (bid * 256 + t) * 4;
        f32x4 v = *(const f32x4*)(x + idx);
        u16x4 o;
        o.x = f2b(v.x); o.y = f2b(v.y); o.z = f2b(v.z); o.w = f2b(v.w);
        *(u16x4*)(xb + idx) = o;
        return;
    }
    int zb = bid - 4096;
    int z = zb >> 10;
    int rem = zb & 1023;
    int bx = rem & 31, by = rem >> 5;
    const float* W = (z == 0) ? Wq : (z == 1) ? Wk : (z == 2) ? Wv : (z == 3) ? Wg : Wo;
    ushort_t* dst = (z < 4) ? (WcatT + (size_t)z * 1024 * 1024) : WoT;
    int n0 = bx * 32, k0 = by * 32;
    int tx = t & 31, ty = t >> 5;
#pragma unroll
    for (int i = 0; i < 4; i++) {
        int k = k0 + ty + i * 8;
        tile[ty + i * 8][tx] = W[(size_t)k * 1024 + n0 + tx];
    }
    __syncthreads();
#pragma unroll
    for (int i = 0; i < 4; i++) {
        int n = n0 + ty + i * 8;
        dst[(size_t)n * 1024 + k0 + tx] = f2b(tile[tx][ty + i * 8]);
    }
}

// ---------------------------------------------------------------- bf16 MFMA GEMM
// C = A @ B, BT[n][k]. BK=64, 32 KB LDS (verified 2 blocks/CU — R7: 49.6 us,
// MfmaUtil 27%, 0 conflicts; BK=128/64KB drops to 1 block/CU and regresses, R8/m132).
// async width=16 staging, XOR-swizzled 16B blocks (key r&7).
// mode 0: N=4096 QKVG epilogue -> Y bf16 (Q*1/8, G = swish(.+bias))
// mode 1: N=1024 -> Fout fp32 = C + bias
__global__ __launch_bounds__(256, 2) void gemm_kernel(
        const ushort_t* __restrict__ A, const ushort_t* __restrict__ BT,
        int K, int N, int mode, const float* __restrict__ bias,
        ushort_t* __restrict__ Yout, float* __restrict__ Fout) {
    extern __shared__ char smem[];
    ushort_t* As = (ushort_t*)smem;          // [128][64] swizzled
    ushort_t* Bs = As + 128 * 64;
    int t = threadIdx.x;
    int row0 = blockIdx.y * 128, col0 = blockIdx.x * 128;
    int w = t >> 6, lane = t & 63;
    int wr = (w >> 1) * 64, wc = (w & 1) * 64;
    int qd = lane >> 4, ln = lane & 15;
    int lx = ln & 7;

    f32x4 acc[4][4];
#pragma unroll
    for (int i = 0; i < 4; i++)
#pragma unroll
        for (int j = 0; j < 4; j++) acc[i][j] = (f32x4)0.0f;

    for (int k0 = 0; k0 < K; k0 += 64) {
#pragma unroll
        for (int p = 0; p < 4; p++) {
            int g = p * 256 + t;
            int r = g >> 3;
            int kb = g & 7;
            int kbs = kb ^ (r & 7);
            async_load16(A + (size_t)(row0 + r) * K + k0 + kbs * 8, As + g * 8);
            async_load16(BT + (size_t)(col0 + r) * K + k0 + kbs * 8, Bs + g * 8);
        }
        __syncthreads();
#pragma unroll
        for (int kk = 0; kk < 64; kk += 32) {
            s16x8 af[4], bf[4];
            int kxa = ((kk >> 3) + qd) ^ lx;
#pragma unroll
            for (int i = 0; i < 4; i++)
                af[i] = *(const s16x8*)(As + (wr + i * 16 + ln) * 64 + kxa * 8);
#pragma unroll
            for (int j = 0; j < 4; j++)
                bf[j] = *(const s16x8*)(Bs + (wc + j * 16 + ln) * 64 + kxa * 8);
#pragma unroll
            for (int i = 0; i < 4; i++)
#pragma unroll
                for (int j = 0; j < 4; j++)
                    acc[i][j] = __builtin_amdgcn_mfma_f32_16x16x32_bf16(
                        af[i], bf[j], acc[i][j], 0, 0, 0);
        }
        __syncthreads();
    }

#pragma unroll
    for (int i = 0; i < 4; i++)
#pragma unroll
        for (int j = 0; j < 4; j++) {
            int n = col0 + wc + j * 16 + ln;
            int region = n >> 10;
#pragma unroll
            for (int r = 0; r < 4; r++) {
                int m = row0 + wr + i * 16 + qd * 4 + r;
                float v = acc[i][j][r];
                if (mode == 0) {
                    if (region == 0) v *= 0.125f;
                    else if (region == 3) {
                        v += bias[n & 1023];
                        v = v / (1.0f + __expf(-v));
                    }
                    Yout[(size_t)m * N + n] = f2b(v);
                } else {
                    Fout[(size_t)m * N + n] = v + bias[n];
                }
            }
        }
}

// ------------------------------------- per-chunk decayed KV state (MFMA), once per chunk
// AstT[d][e] = sum_j V[j][d] * K[j][e] * g^(127-j);  M=64(d), N=64(e), K=128(j)
#define SJ 136
__global__ __launch_bounds__(256) void chunk_states_kernel(const ushort_t* __restrict__ Y,
                                                           float* __restrict__ Astate) {
    __shared__ ushort_t Ktd[64 * SJ];   // [e][j]  decayed K^T
    __shared__ ushort_t Vtd[64 * SJ];   // [d][j]  V^T
    int c = blockIdx.x, h = blockIdx.y, b = blockIdx.z;
    int t = threadIdx.x;
    float gamma = 1.0f - exp2f(-5.0f - (float)h);
    float l2g = log2f(gamma);
    int row0 = b * SEQ + c * CHUNK;
    int colK = D_MODEL + h * HDIM;

    {
        int dgi = t & 7, jg = t >> 3;
        u16x8 k8[4], v8[4];
        float dec[4];
#pragma unroll
        for (int r = 0; r < 4; r++) {
            int j = jg * 4 + r;
            size_t src = (size_t)(row0 + j) * 4096 + colK + dgi * 8;
            k8[r] = *(const u16x8*)(Y + src);
            v8[r] = *(const u16x8*)(Y + src + D_MODEL);
            dec[r] = exp2f((float)(127 - j) * l2g);
        }
#pragma unroll
        for (int q = 0; q < 8; q++) {
            int qq = q ^ dgi;                   // bank-decorrelating permutation
            u16x4 pk, pv;
#pragma unroll
            for (int r = 0; r < 4; r++) {
                pk[r] = f2b(b2f(k8[r][qq]) * dec[r]);
                pv[r] = v8[r][qq];
            }
            *(u16x4*)(Ktd + (dgi * 8 + qq) * SJ + jg * 4) = pk;
            *(u16x4*)(Vtd + (dgi * 8 + qq) * SJ + jg * 4) = pv;
        }
    }
    __syncthreads();

    int w = t >> 6, lane = t & 63;
    int wr = w * 16;                 // this wave's 16 d-rows
    int qd = lane >> 4, ln = lane & 15;

    s16x8 af[4];
#pragma unroll
    for (int ks = 0; ks < 4; ks++)
        af[ks] = *(const s16x8*)(Vtd + (wr + ln) * SJ + ks * 32 + qd * 8);

    f32x4 acc[4];
#pragma unroll
    for (int nt = 0; nt < 4; nt++) {
        acc[nt] = (f32x4)0.0f;
#pragma unroll
        for (int ks = 0; ks < 4; ks++) {
            s16x8 bf = *(const s16x8*)(Ktd + (nt * 16 + ln) * SJ + ks * 32 + qd * 8);
            acc[nt] = __builtin_amdgcn_mfma_f32_16x16x32_bf16(af[ks], bf, acc[nt], 0, 0, 0);
        }
    }

    size_t base = ((size_t)((b * NHEADS + h) * NCHUNK + c)) * 4096;
#pragma unroll
    for (int nt = 0; nt < 4; nt++)
#pragma unroll
        for (int r = 0; r < 4; r++)
            Astate[base + (size_t)(wr + qd * 4 + r) * 64 + nt * 16 + ln] = acc[nt][r];
}

// --------------------------------------------- retention output (prefix-combine + MFMA)
// S_prev = sum_{cp<c} gC^(c-1-cp) A_cp  (elementwise, registers, prefetched)
// out[i][d] = g^(i+1)*(Q_i.S[:,d]) + sum_{j<=i} g^(i-j)(Q_i.K_j)V_j[d]
// ret written bf16; per-row (sum,sumsq) of rounded values atomically -> rowstats.
#define LDW 72
#define VT_LDW 136
#define CO_ELEMS (128*LDW*2 + 64*LDW*2 + 64*VT_LDW)   // 36352 elems = 72704 B
__global__ __launch_bounds__(256, 2) void retention_kernel(const ushort_t* __restrict__ Y,
                                                           const float* __restrict__ Astate,
                                                           ushort_t* __restrict__ ret,
                                                           float* __restrict__ rowstats) {
    extern __shared__ char smem[];
    ushort_t* Qs   = (ushort_t*)smem;            // [128][72]
    ushort_t* Kc   = Qs + 128 * LDW;             // [128][72]
    ushort_t* Sphi = Kc + 128 * LDW;             // [64][72]   S^T hi [d][e]
    ushort_t* Splo = Sphi + 64 * LDW;            // [64][72]   S^T lo
    ushort_t* Vt   = Splo + 64 * LDW;            // [64][136]  V^T[d][j] (chunk c)
    ushort_t* Pl   = Qs;                         // [128][136] phase-3 overlay

    int bx = blockIdx.x, h = blockIdx.y, b = blockIdx.z;
    // pair-balance: consecutive bx pairs sum to NCHUNK-1 so co-resident blocks
    // average 7.5 prefix stages instead of 0..15 skew
    int c = (bx & 1) ? (NCHUNK - 1 - (bx >> 1)) : (bx >> 1);
    int t = threadIdx.x;
    float gamma = 1.0f - exp2f(-5.0f - (float)h);
    float l2g = log2f(gamma);
    float gC = exp2f(128.0f * l2g);
    int row0 = b * SEQ + c * CHUNK;

    int w = t >> 6, lane = t & 63;
    int qd = lane >> 4, ln = lane & 15;
    int dgi = t & 7, jg = t >> 3;

    // ---- stage V_c transposed into Vt
    {
        u16x8 v8[4];
#pragma unroll
        for (int r = 0; r < 4; r++)
            v8[r] = *(const u16x8*)(Y + (size_t)(row0 + jg * 4 + r) * 4096
                                      + 2 * D_MODEL + h * HDIM + dgi * 8);
#pragma unroll
        for (int q = 0; q < 8; q++) {
            int qq = q ^ dgi;
            u16x4 pv;
#pragma unroll
            for (int r = 0; r < 4; r++) pv[r] = v8[r][qq];
            *(u16x4*)(Vt + (dgi * 8 + qq) * VT_LDW + jg * 4) = pv;
        }
    }

    // ---- stage Q,K (row-major)
    for (int g = t; g < 1024; g += 256) {
        int i = g >> 3, dg = (g & 7) * 8;
        size_t src = (size_t)(row0 + i) * 4096 + h * HDIM + dg;
        *(u16x8*)(Qs + i * LDW + dg) = *(const u16x8*)(Y + src);
        *(u16x8*)(Kc + i * LDW + dg) = *(const u16x8*)(Y + src + D_MODEL);
    }

    // ---- prefix combine: S = S*gC + A_cp (register double-buffered prefetch)
    {
        f32x4 acc4[4];
#pragma unroll
        for (int k4 = 0; k4 < 4; k4++) acc4[k4] = (f32x4)0.0f;
        size_t abase = ((size_t)((b * NHEADS + h) * NCHUNK)) * 4096 + t * 16;
        f32x4 a_cur[4];
        if (c > 0) {
#pragma unroll
            for (int k4 = 0; k4 < 4; k4++)
                a_cur[k4] = *(const f32x4*)(Astate + abase + k4 * 4);
        }
        for (int cp = 0; cp < c; cp++) {
            f32x4 a_nxt[4];
            if (cp + 1 < c) {
#pragma unroll
                for (int k4 = 0; k4 < 4; k4++)
                    a_nxt[k4] = *(const f32x4*)(Astate + abase + (size_t)(cp + 1) * 4096 + k4 * 4);
            }
#pragma unroll
            for (int k4 = 0; k4 < 4; k4++)
                acc4[k4] = acc4[k4] * gC + a_cur[k4];
#pragma unroll
            for (int k4 = 0; k4 < 4; k4++) a_cur[k4] = a_nxt[k4];
        }
        int d = t >> 2, e0 = (t & 3) * 16;
#pragma unroll
        for (int k4 = 0; k4 < 4; k4++) {
            u16x4 hi4, lo4;
#pragma unroll
            for (int k2 = 0; k2 < 4; k2++) {
                float s = acc4[k4][k2];
                ushort_t hb = f2b(s);
                hi4[k2] = hb;
                lo4[k2] = f2b(s - b2f(hb));
            }
            *(u16x4*)(Sphi + d * LDW + e0 + k4 * 4) = hi4;
            *(u16x4*)(Splo + d * LDW + e0 + k4 * 4) = lo4;
        }
    }
    __syncthreads();

    int wr2 = w * 32;    // wave's 32 output rows

    s16x8 aq[2][2];
#pragma unroll
    for (int mt = 0; mt < 2; mt++)
#pragma unroll
        for (int ks = 0; ks < 2; ks++)
            aq[mt][ks] = *(const s16x8*)(Qs + (wr2 + mt * 16 + ln) * LDW + ks * 32 + qd * 8);

    float prow[2][4], pcolm[8];
#pragma unroll
    for (int mt = 0; mt < 2; mt++)
#pragma unroll
        for (int r = 0; r < 4; r++)
            prow[mt][r] = exp2f((float)(wr2 + mt * 16 + qd * 4 + r + 1) * l2g);
#pragma unroll
    for (int nt = 0; nt < 8; nt++)
        pcolm[nt] = exp2f(-(float)(nt * 16 + ln + 1) * l2g);

    // phase 1: out = Q @ S (hi+lo), scaled g^(i+1)
    f32x4 out[2][4];
#pragma unroll
    for (int mt = 0; mt < 2; mt++)
#pragma unroll
        for (int dt = 0; dt < 4; dt++) out[mt][dt] = (f32x4)0.0f;
#pragma unroll
    for (int dt = 0; dt < 4; dt++)
#pragma unroll
        for (int ks = 0; ks < 2; ks++) {
            s16x8 bh_ = *(const s16x8*)(Sphi + (dt * 16 + ln) * LDW + ks * 32 + qd * 8);
            s16x8 bl_ = *(const s16x8*)(Splo + (dt * 16 + ln) * LDW + ks * 32 + qd * 8);
#pragma unroll
            for (int mt = 0; mt < 2; mt++) {
                out[mt][dt] = __builtin_amdgcn_mfma_f32_16x16x32_bf16(
                    aq[mt][ks], bh_, out[mt][dt], 0, 0, 0);
                out[mt][dt] = __builtin_amdgcn_mfma_f32_16x16x32_bf16(
                    aq[mt][ks], bl_, out[mt][dt], 0, 0, 0);
            }
        }
#pragma unroll
    for (int mt = 0; mt < 2; mt++)
#pragma unroll
        for (int dt = 0; dt < 4; dt++)
#pragma unroll
            for (int r = 0; r < 4; r++) out[mt][dt][r] *= prow[mt][r];

    // phase 2: scores = Q @ K^T
    f32x4 sc[2][8];
#pragma unroll
    for (int mt = 0; mt < 2; mt++)
#pragma unroll
        for (int nt = 0; nt < 8; nt++) sc[mt][nt] = (f32x4)0.0f;
#pragma unroll
    for (int nt = 0; nt < 8; nt++)
#pragma unroll
        for (int ks = 0; ks < 2; ks++) {
            s16x8 bk = *(const s16x8*)(Kc + (nt * 16 + ln) * LDW + ks * 32 + qd * 8);
#pragma unroll
            for (int mt = 0; mt < 2; mt++)
                sc[mt][nt] = __builtin_amdgcn_mfma_f32_16x16x32_bf16(
                    aq[mt][ks], bk, sc[mt][nt], 0, 0, 0);
        }
    __syncthreads();

    // decay-mask, P bf16 -> LDS (A-operand layout)
#pragma unroll
    for (int mt = 0; mt < 2; mt++)
#pragma unroll
        for (int nt = 0; nt < 8; nt++) {
            int j = nt * 16 + ln;
#pragma unroll
            for (int r = 0; r < 4; r++) {
                int i = wr2 + mt * 16 + qd * 4 + r;
                float v = (j <= i) ? sc[mt][nt][r] * (prow[mt][r] * pcolm[nt]) : 0.0f;
                Pl[i * VT_LDW + j] = f2b(v);
            }
        }
    __syncthreads();

    // phase 3: out += P @ V
#pragma unroll
    for (int ks = 0; ks < 4; ks++) {
        s16x8 ap[2];
#pragma unroll
        for (int mt = 0; mt < 2; mt++)
            ap[mt] = *(const s16x8*)(Pl + (wr2 + mt * 16 + ln) * VT_LDW + ks * 32 + qd * 8);
#pragma unroll
        for (int dt = 0; dt < 4; dt++) {
            s16x8 bv = *(const s16x8*)(Vt + (dt * 16 + ln) * VT_LDW + ks * 32 + qd * 8);
#pragma unroll
            for (int mt = 0; mt < 2; mt++)
                out[mt][dt] = __builtin_amdgcn_mfma_f32_16x16x32_bf16(
                    ap[mt], bv, out[mt][dt], 0, 0, 0);
        }
    }

    // ---- store bf16 + per-row LN stats of the ROUNDED values
    float psum[2][4], psq[2][4];
#pragma unroll
    for (int mt = 0; mt < 2; mt++)
#pragma unroll
        for (int r = 0; r < 4; r++) { psum[mt][r] = 0.0f; psq[mt][r] = 0.0f; }
#pragma unroll
    for (int mt = 0; mt < 2; mt++)
#pragma unroll
        for (int dt = 0; dt < 4; dt++)
#pragma unroll
            for (int r = 0; r < 4; r++) {
                int i = wr2 + mt * 16 + qd * 4 + r;
                ushort_t hb = f2b(out[mt][dt][r]);
                ret[(size_t)(row0 + i) * D_MODEL + h * HDIM + dt * 16 + ln] = hb;
                float vr = b2f(hb);
                psum[mt][r] += vr;
                psq[mt][r]  += vr * vr;
            }
#pragma unroll
    for (int m = 1; m < 16; m <<= 1)
#pragma unroll
        for (int mt = 0; mt < 2; mt++)
#pragma unroll
            for (int r = 0; r < 4; r++) {
                psum[mt][r] += __shfl_xor(psum[mt][r], m);
                psq[mt][r]  += __shfl_xor(psq[mt][r], m);
            }
    if (ln == 0) {
#pragma unroll
        for (int mt = 0; mt < 2; mt++)
#pragma unroll
            for (int r = 0; r < 4; r++) {
                int i = row0 + wr2 + mt * 16 + qd * 4 + r;
                atomicAdd(rowstats + 2 * i,     psum[mt][r]);
                atomicAdd(rowstats + 2 * i + 1, psq[mt][r]);
            }
    }
}

// ----------------------------------- LayerNorm * gate (elementwise, stats precomputed)
__global__ __launch_bounds__(256) void ln_gate_kernel(const ushort_t* __restrict__ ret,
                                                      const ushort_t* __restrict__ Y,
                                                      const float* __restrict__ rowstats,
                                                      const float* __restrict__ lgam,
                                                      const float* __restrict__ lbet,
                                                      ushort_t* __restrict__ LNG) {
    int row = blockIdx.x, t = threadIdx.x;
    float s  = rowstats[2 * row];
    float sq = rowstats[2 * row + 1];
    float mu  = s * (1.0f / 1024.0f);
    float var = sq * (1.0f / 1024.0f) - mu * mu;
    float inv = rsqrtf(var + LN_EPS);
    int col = t * 4;
    u16x4 rv = *(const u16x4*)(ret + (size_t)row * D_MODEL + col);
    u16x4 ug = *(const u16x4*)(Y + (size_t)row * 4096 + 3 * D_MODEL + col);
    f32x4 ga = *(const f32x4*)(lgam + col);
    f32x4 gb = *(const f32x4*)(lbet + col);
    u16x4 o;
#pragma unroll
    for (int k = 0; k < 4; k++)
        o[k] = f2b(((b2f(rv[k]) - mu) * inv * ga[k] + gb[k]) * b2f(ug[k]));
    *(u16x4*)(LNG + (size_t)row * D_MODEL + col) = o;
}

// ----------------------------------------------------------------------------
extern "C" void kernel_launch(void* const* d_in, const int* in_sizes, int n_in,
                              void* d_out, int out_size, void* d_ws, size_t ws_size,
                              hipStream_t stream) {
    const float* x   = (const float*)d_in[0];
    const float* Wq  = (const float*)d_in[1];
    const float* Wk  = (const float*)d_in[2];
    const float* Wv  = (const float*)d_in[3];
    const float* Wg  = (const float*)d_in[4];
    const float* bg  = (const float*)d_in[5];
    const float* Wo  = (const float*)d_in[6];
    const float* bo  = (const float*)d_in[7];
    const float* lng = (const float*)d_in[8];
    const float* lnb = (const float*)d_in[9];
    float* out = (float*)d_out;

    char* ws = (char*)d_ws;
    ushort_t* xb    = (ushort_t*)(ws);                       //  8 MB  x bf16
    ushort_t* WcatT = (ushort_t*)(ws + (8ull  << 20));       //  8 MB  [Wq|Wk|Wv|Wg]^T bf16
    ushort_t* WoT   = (ushort_t*)(ws + (16ull << 20));       //  2 MB  Wo^T bf16
    ushort_t* Yb    = (ushort_t*)(ws + (18ull << 20));       // 32 MB  [Q/8|K|V|G] bf16
    float*    rstat = (float*)   (ws + (50ull << 20));       // 32 KB  per-row (sum, sumsq)
    ushort_t* retb  = (ushort_t*)(ws + (51ull << 20));       //  8 MB  retention out bf16
    ushort_t* LNGb  = (ushort_t*)(ws + (60ull << 20));       //  8 MB  (ln*G) bf16
    float*    Ast   = (float*)   (ws + (69ull << 20));       //  8 MB  chunk states [d][e] fp32

    const int GEMM_LDS = 2 * 128 * 64 * 2;                   // 32768 B (BK=64, 2 blocks/CU)
    const int CO_BYTES = CO_ELEMS * 2;                       // 72704 B

    hipFuncSetAttribute(reinterpret_cast<const void*>(gemm_kernel),
                        hipFuncAttributeMaxDynamicSharedMemorySize, GEMM_LDS);
    hipFuncSetAttribute(reinterpret_cast<const void*>(retention_kernel),
                        hipFuncAttributeMaxDynamicSharedMemorySize, CO_BYTES);

    prep_kernel<<<4096 + 5120, 256, 0, stream>>>(x, Wq, Wk, Wv, Wg, Wo,
                                                 xb, WcatT, WoT, rstat);

    gemm_kernel<<<dim3(32, 32), 256, GEMM_LDS, stream>>>(
        xb, WcatT, 1024, 4096, 0, bg, Yb, (float*)nullptr);

    chunk_states_kernel<<<dim3(NCHUNK, NHEADS, BATCH), 256, 0, stream>>>(Yb, Ast);

    retention_kernel<<<dim3(NCHUNK, NHEADS, BATCH), 256, CO_BYTES, stream>>>(
        Yb, Ast, retb, rstat);

    ln_gate_kernel<<<ROWS, 256, 0, stream>>>(retb, Yb, rstat, lng, lnb, LNGb);

    gemm_kernel<<<dim3(8, 32), 256, GEMM_LDS, stream>>>(
        LNGb, WoT, 1024, 1024, 1, bo, (ushort_t*)nullptr, out);
}